// Round 1
// baseline (261.862 us; speedup 1.0000x reference)
//
#include <hip/hip_runtime.h>

// Rotation by label: B=256, C=3, H=W=224 fp32.
//   lab 0: out[h][w] = in[h][w]
//   lab 1: out[h][w] = in[w][h]            (transpose)
//   lab 2: out[h][w] = in[223-h][w]        (flip rows)
//   lab 3: out[h][w] = in[223-w][h]        (transpose + flip cols)
// 32x32 LDS tile transpose for lab 1/3; straight float4 copy for lab 0/2.
// Label is uniform per block (depends only on b) -> no divergence.

#define HW 224
#define TILE 32
#define NT 7  // 224 / 32

__global__ __launch_bounds__(256) void rot4_kernel(const float* __restrict__ x,
                                                   const int* __restrict__ label,
                                                   float* __restrict__ out) {
    int tile = blockIdx.x;
    int tw = tile % NT; tile /= NT;        // tile col
    int th = tile % NT; tile /= NT;        // tile row
    int c  = tile % 3;  tile /= 3;         // channel
    int b  = tile;                         // batch

    const int lab = label[b];              // block-uniform
    const size_t plane = (size_t)(b * 3 + c) * (HW * HW);
    const float* __restrict__ in = x + plane;
    float* __restrict__ o = out + plane;

    const int h0 = th * TILE;
    const int w0 = tw * TILE;

    const int t  = threadIdx.x;
    const int r  = t >> 3;                 // 0..31 tile row
    const int c4 = t & 7;                  // 0..7  float4 col within tile

    if (lab == 0 || lab == 2) {
        // coalesced float4 copy, optional row flip
        const int in_row = (lab == 0) ? (h0 + r) : (HW - 1 - (h0 + r));
        float4 v = *(const float4*)(in + (size_t)in_row * HW + w0 + c4 * 4);
        *(float4*)(o + (size_t)(h0 + r) * HW + w0 + c4 * 4) = v;
    } else {
        // transpose via LDS tile; stride 33 -> <=2-way bank aliasing (free on wave64)
        __shared__ float tb[TILE][TILE + 1];
        // source tile rows: lab==1 -> [w0, w0+32); lab==3 -> [192-w0, 224-w0)
        const int rbase = (lab == 1) ? w0 : (HW - TILE - w0);
        float4 v = *(const float4*)(in + (size_t)(rbase + r) * HW + h0 + c4 * 4);
        tb[r][c4 * 4 + 0] = v.x;
        tb[r][c4 * 4 + 1] = v.y;
        tb[r][c4 * 4 + 2] = v.z;
        tb[r][c4 * 4 + 3] = v.w;
        __syncthreads();
        float4 w;
        if (lab == 1) {
            // out[h0+r][w0+4c4+j] = in[w0+4c4+j][h0+r] = tb[4c4+j][r]
            w.x = tb[c4 * 4 + 0][r];
            w.y = tb[c4 * 4 + 1][r];
            w.z = tb[c4 * 4 + 2][r];
            w.w = tb[c4 * 4 + 3][r];
        } else {
            // out[h0+r][w0+4c4+j] = in[223-w0-4c4-j][h0+r] = tb[31-4c4-j][r]
            w.x = tb[31 - (c4 * 4 + 0)][r];
            w.y = tb[31 - (c4 * 4 + 1)][r];
            w.z = tb[31 - (c4 * 4 + 2)][r];
            w.w = tb[31 - (c4 * 4 + 3)][r];
        }
        *(float4*)(o + (size_t)(h0 + r) * HW + w0 + c4 * 4) = w;
    }
}

// Second tuple element: label, written as float values (harness reads the
// whole d_out buffer as float32).
__global__ void label_kernel(const int* __restrict__ label, float* __restrict__ out, int n) {
    int i = blockIdx.x * blockDim.x + threadIdx.x;
    if (i < n) out[i] = (float)label[i];
}

extern "C" void kernel_launch(void* const* d_in, const int* in_sizes, int n_in,
                              void* d_out, int out_size, void* d_ws, size_t ws_size,
                              hipStream_t stream) {
    const float* x     = (const float*)d_in[0];
    const int*   label = (const int*)d_in[1];
    float*       out   = (float*)d_out;

    const int B = in_sizes[1];             // 256
    const int nblocks = B * 3 * NT * NT;   // one block per 32x32 tile per (b,c)

    rot4_kernel<<<nblocks, 256, 0, stream>>>(x, label, out);

    const size_t img_elems = (size_t)B * 3 * HW * HW;
    label_kernel<<<(B + 255) / 256, 256, 0, stream>>>(label, out + img_elems, B);
}